// Round 6
// baseline (215.092 us; speedup 1.0000x reference)
//
#include <hip/hip_runtime.h>
#include <hip/hip_cooperative_groups.h>
#include <hip/hip_bf16.h>
#include <math.h>

namespace cg = cooperative_groups;

// Problem dims (fixed by reference)
#define B_SZ 256
#define P_SZ 256
#define LD   128   // L_DIM (evolving part)
#define ZD   256   // Z_DIM
#define HD   256   // H_DIM
#define OB   16    // batch rows per ODE block (MFMA M dim)
#define DPTS 128   // points per decode half
#define NODE 16    // # ODE blocks in fused grid
#define GRID_F 256 // fused grid size (1 block per batch row)
// R6: fused-v2. R5's fail was either cooperative-launch rejection (out=zeros,
// 0.867 = max|mu_ref|) or cross-XCD staleness on intra-kernel handoffs.
// Fixes: (1) pack remains a SEPARATE prior kernel -> pack->ODE coherence is
// guaranteed at the kernel boundary; (2) the only intra-kernel handoff
// (dstate) uses agent-scope release/acquire atomics (the architected
// mechanism per XCD non-coherence rules); (3) grid = 256 blocks x 256 thr,
// 1/CU trivially co-resident -> acceptance near-certain; each block does one
// batch row, BOTH halves (dedups Breg/zh/sv4 staging vs the 512-block form);
// (4) rc-checked fallback to the R2-verified ode/decode kernels.
// Integrator unchanged (single Heun step, Hermite right slope = predictor
// slope k2); absmax floor = bf16 latent quantization (0.0078125).

typedef __attribute__((ext_vector_type(8))) short short8;   // 8 bf16 = 4 VGPRs
typedef __attribute__((ext_vector_type(4))) float v4f;      // mfma C/D

__device__ __forceinline__ float fast_tanh(float v) {
  float e = __expf(2.0f * fabsf(v));
  float r = 1.0f - 2.0f / (e + 1.0f);
  return copysignf(r, v);
}

__device__ __forceinline__ unsigned int bf_bits(float f) {
  unsigned int u = __float_as_uint(f);
  return (u + 0x7fffu + ((u >> 16) & 1u)) >> 16;   // RNE
}
__device__ __forceinline__ float bf_lo(unsigned int u) {
  return __uint_as_float(u << 16);
}
__device__ __forceinline__ float bf_hi(unsigned int u) {
  return __uint_as_float(u & 0xffff0000u);
}

// Build one MFMA B-fragment in lane order: lane (col,quad) holds
// B[k = kb..kb+7][n], kb = ks*32 + quad*8, as 8 bf16 (RNE from f32).
__device__ __forceinline__ short8 pack_bfrag(const float* __restrict__ W,
                                             int stride, int kb, int n) {
  short8 r;
#pragma unroll
  for (int jj = 0; jj < 8; jj++)
    r[jj] = (short)bf_bits(W[(kb + jj) * stride + n]);
  return r;
}

// ---------------------------------------------------------------------------
// Pack: 80 blocks pack the ODE weights into MFMA B-fragment lane order.
// Separate kernel => its writes are coherent for the next kernel (boundary
// flush/inv by the runtime) — no intra-kernel weight handoff needed.
// ---------------------------------------------------------------------------
__global__ __launch_bounds__(256) void pack_kernel(
    const float* __restrict__ W1, const float* __restrict__ W2,
    const float* __restrict__ W3,
    uint4* __restrict__ W1B, uint4* __restrict__ W1hB,
    uint4* __restrict__ W2B, uint4* __restrict__ W3B)
{
  int idx = blockIdx.x * 256 + threadIdx.x;
  const float* src; int stride, kb, n; uint4* dst; int di;
  if (idx < 4096) {            // W1B: K=128, N=256, f = nt*4+ks
    int i = idx, l = i & 63, f = i >> 6;
    int ks = f & 3, nt = f >> 2;
    n = nt * 16 + (l & 15); kb = ks * 32 + (l >> 4) * 8;
    src = W1; stride = HD; dst = W1B; di = i;
  } else if (idx < 8192) {     // W1hB: W1 rows 128..255
    int i = idx - 4096, l = i & 63, f = i >> 6;
    int ks = f & 3, nt = f >> 2;
    n = nt * 16 + (l & 15); kb = 128 + ks * 32 + (l >> 4) * 8;
    src = W1; stride = HD; dst = W1hB; di = i;
  } else if (idx < 16384) {    // W2B: K=256, N=256, f = nt*8+ks
    int i = idx - 8192, l = i & 63, f = i >> 6;
    int ks = f & 7, nt = f >> 3;
    n = nt * 16 + (l & 15); kb = ks * 32 + (l >> 4) * 8;
    src = W2; stride = HD; dst = W2B; di = i;
  } else {                     // W3B: K=256, N=128, f = nt*8+ks
    int i = idx - 16384, l = i & 63, f = i >> 6;
    int ks = f & 7, nt = f >> 3;
    n = nt * 16 + (l & 15); kb = ks * 32 + (l >> 4) * 8;
    src = W3; stride = LD; dst = W3B; di = i;
  }
  uint4 o;
  o.x = bf_bits(src[(kb + 0) * stride + n]) | (bf_bits(src[(kb + 1) * stride + n]) << 16);
  o.y = bf_bits(src[(kb + 2) * stride + n]) | (bf_bits(src[(kb + 3) * stride + n]) << 16);
  o.z = bf_bits(src[(kb + 4) * stride + n]) | (bf_bits(src[(kb + 5) * stride + n]) << 16);
  o.w = bf_bits(src[(kb + 6) * stride + n]) | (bf_bits(src[(kb + 7) * stride + n]) << 16);
  dst[di] = o;
}

// ---------------------------------------------------------------------------
// Fallback kernel A (R2-verified): MFMA ODE, 16 blocks x 1024 threads.
// ---------------------------------------------------------------------------
__global__ __launch_bounds__(1024, 1) void ode_kernel(
    const float* __restrict__ x, const float* __restrict__ z,
    const float* __restrict__ x0,
    const float* __restrict__ W1, const float* __restrict__ b1,
    const float* __restrict__ b2, const float* __restrict__ b3,
    const short8* __restrict__ W1B, const short8* __restrict__ W1hB,
    const short8* __restrict__ W2B, const short8* __restrict__ W3B,
    float* __restrict__ dstate)
{
  __shared__ float vL[OB][LD];
  __shared__ float kb0[OB][LD], kb1[OB][LD];
  __shared__ short vinA[OB * 136];
  __shared__ short h1A[OB * 264];
  __shared__ short h2A[OB * 264];

  const int tid  = threadIdx.x;
  const int b0   = blockIdx.x * OB;
  const int w    = tid >> 6;
  const int l    = tid & 63;
  const int col  = l & 15;
  const int quad = l >> 4;
  const int u12  = w * 16 + col;

  short8 B1fr[4], B2fr[8];
#pragma unroll
  for (int ks = 0; ks < 4; ks++) B1fr[ks] = W1B[(w * 4 + ks) * 64 + l];
#pragma unroll
  for (int ks = 0; ks < 8; ks++) B2fr[ks] = W2B[(w * 8 + ks) * 64 + l];

  {
    unsigned int* vinU = (unsigned int*)vinA;
    int r = tid >> 6, kd = tid & 63;
    vL[r][2 * kd]     = z[(b0 + r) * ZD + 2 * kd];
    vL[r][2 * kd + 1] = z[(b0 + r) * ZD + 2 * kd + 1];
    kb0[r][2 * kd] = 0.f; kb0[r][2 * kd + 1] = 0.f;
    float f0 = z[(b0 + r) * ZD + LD + 2 * kd];
    float f1 = z[(b0 + r) * ZD + LD + 2 * kd + 1];
    vinU[r * 68 + kd] = bf_bits(f0) | (bf_bits(f1) << 16);
  }
  const float tv0 = x0[0];
  const float tv1 = x[P_SZ - 1];
  __syncthreads();

  v4f c1r = (v4f){0.f, 0.f, 0.f, 0.f};
  {
    short8 af[4];
#pragma unroll
    for (int ks = 0; ks < 4; ks++)
      af[ks] = *(const short8*)&vinA[col * 136 + ks * 32 + quad * 8];
#pragma unroll
    for (int ks = 0; ks < 4; ks++)
      c1r = __builtin_amdgcn_mfma_f32_16x16x32_bf16(
          af[ks], W1hB[(w * 4 + ks) * 64 + l], c1r, 0, 0, 0);
  }
  {
    float b1u = b1[u12];
#pragma unroll
    for (int r = 0; r < 4; r++) c1r[r] += b1u;
  }
  const float w1tr = W1[ZD * HD + u12];
  const float b2r  = b2[u12];
  const float b3r  = (w < 8) ? b3[w * 16 + col] : 0.f;
  __syncthreads();

  auto eval_f = [&](float t, float (*vsrc)[LD], float (*kin)[LD], float c,
                    float (*kout)[LD]) {
    {
      unsigned int* vinU = (unsigned int*)vinA;
      int r = tid >> 6, kd = tid & 63;
      float v0 = vsrc[r][2 * kd]     + c * kin[r][2 * kd];
      float v1 = vsrc[r][2 * kd + 1] + c * kin[r][2 * kd + 1];
      vinU[r * 68 + kd] = bf_bits(v0) | (bf_bits(v1) << 16);
    }
    __syncthreads();
    {
      short8 a1[4];
#pragma unroll
      for (int ks = 0; ks < 4; ks++)
        a1[ks] = *(const short8*)&vinA[col * 136 + ks * 32 + quad * 8];
      v4f acc = (v4f){0.f, 0.f, 0.f, 0.f};
#pragma unroll
      for (int ks = 0; ks < 4; ks++)
        acc = __builtin_amdgcn_mfma_f32_16x16x32_bf16(a1[ks], B1fr[ks], acc, 0, 0, 0);
      float tw = t * w1tr;
#pragma unroll
      for (int r = 0; r < 4; r++) {
        float h = fast_tanh(acc[r] + c1r[r] + tw);
        h1A[(quad * 4 + r) * 264 + u12] = (short)bf_bits(h);
      }
    }
    __syncthreads();
    {
      short8 a2[8];
#pragma unroll
      for (int ks = 0; ks < 8; ks++)
        a2[ks] = *(const short8*)&h1A[col * 264 + ks * 32 + quad * 8];
      v4f acc = (v4f){0.f, 0.f, 0.f, 0.f};
#pragma unroll
      for (int ks = 0; ks < 8; ks++)
        acc = __builtin_amdgcn_mfma_f32_16x16x32_bf16(a2[ks], B2fr[ks], acc, 0, 0, 0);
#pragma unroll
      for (int r = 0; r < 4; r++) {
        float h = fast_tanh(acc[r] + b2r);
        h2A[(quad * 4 + r) * 264 + u12] = (short)bf_bits(h);
      }
    }
    __syncthreads();
    if (w < 8) {
      short8 a3[8];
#pragma unroll
      for (int ks = 0; ks < 8; ks++)
        a3[ks] = *(const short8*)&h2A[col * 264 + ks * 32 + quad * 8];
      v4f acc = (v4f){0.f, 0.f, 0.f, 0.f};
#pragma unroll
      for (int ks = 0; ks < 8; ks++)
        acc = __builtin_amdgcn_mfma_f32_16x16x32_bf16(
            a3[ks], W3B[(w * 8 + ks) * 64 + l], acc, 0, 0, 0);
      int u = w * 16 + col;
#pragma unroll
      for (int r = 0; r < 4; r++)
        kout[quad * 4 + r][u] = acc[r] + b3r;
    }
    __syncthreads();
  };

  const float H = tv1 - tv0;
  eval_f(tv0, vL, kb0, 0.f, kb0);
  eval_f(tv1, vL, kb0, H,   kb1);

  {
    int idx = tid;
#pragma unroll
    for (int it = 0; it < 2; it++, idx += 1024) {
      int r = idx >> 7, k = idx & 127;
      float vl = vL[r][k], k0 = kb0[r][k], k1v = kb1[r][k];
      float vn = vl + 0.5f * H * (k0 + k1v);
      size_t base = (size_t)(b0 + r) * 512 + k;
      dstate[base]       = vl;
      dstate[base + 128] = k0;
      dstate[base + 256] = vn;
      dstate[base + 384] = k1v;
    }
  }
}

// ---------------------------------------------------------------------------
// Fallback kernel B (R2-verified): decode, 512 blocks x 256 threads.
// ---------------------------------------------------------------------------
__global__ __launch_bounds__(256, 2) void decode_kernel(
    const float* __restrict__ x, const float* __restrict__ x0,
    const float* __restrict__ dstate,
    const float* __restrict__ z, const float* __restrict__ Wh,
    const float* __restrict__ bh,
    const float* __restrict__ Wmu, const float* __restrict__ bmu,
    const float* __restrict__ Wsig, const float* __restrict__ bsig,
    float* __restrict__ out)
{
  const int b  = blockIdx.y;
  const int p0 = blockIdx.x * DPTS;
  const int j  = threadIdx.x;

  __shared__ short latA[DPTS * 136];
  __shared__ float sv4[4][LD];
  __shared__ float xv[DPTS];
  __shared__ float zr[LD];
  __shared__ float zhs[HD], wh0s[HD];
  __shared__ float wmus[384], wsgs[384];
  __shared__ float pmu[4][DPTS], psg[4][DPTS];

  const int w    = j >> 6;
  const int l    = j & 63;
  const int col  = l & 15;
  const int quad = l >> 4;

  for (int idx = j; idx < 512; idx += 256)
    sv4[idx >> 7][idx & 127] = dstate[(size_t)b * 512 + idx];
  if (j < DPTS) {
    xv[j] = x[b * P_SZ + p0 + j];
    zr[j] = z[b * ZD + LD + j];
  }
  wh0s[j] = Wh[j];
  for (int idx = j; idx < 384; idx += 256) {
    wmus[idx] = Wmu[idx];
    wsgs[idx] = Wsig[idx];
  }

  short8 Breg[4][4];
#pragma unroll
  for (int i = 0; i < 4; i++)
#pragma unroll
    for (int ks = 0; ks < 4; ks++)
      Breg[i][ks] = pack_bfrag(Wh + HD, HD, ks * 32 + quad * 8,
                               (w * 4 + i) * 16 + col);

  __syncthreads();

  {
    float acc = bh[j];
#pragma unroll 8
    for (int k = 0; k < LD; k += 4) {
      float4 zv = *(const float4*)&zr[k];
      acc += zv.x * Wh[(LD + 1 + k) * HD + j] + zv.y * Wh[(LD + 2 + k) * HD + j]
           + zv.z * Wh[(LD + 3 + k) * HD + j] + zv.w * Wh[(LD + 4 + k) * HD + j];
    }
    zhs[j] = acc;
  }

  {
    const float t0 = x0[0];
    const float t1 = x[b * P_SZ + P_SZ - 1];
    const float H = t1 - t0, invH = 1.0f / H;
    unsigned int* latu = (unsigned int*)latA;
    for (int idx = j; idx < DPTS * 64; idx += 256) {
      int t = idx >> 6, kd = idx & 63;
      float s  = (xv[t] - t0) * invH;
      float s2 = s * s, s3 = s2 * s;
      float h00 = 2.f * s3 - 3.f * s2 + 1.f;
      float h10H = (s3 - 2.f * s2 + s) * H;
      float h01 = 3.f * s2 - 2.f * s3;
      float h11H = (s3 - s2) * H;
      float v0 = h00 * sv4[0][2 * kd]     + h10H * sv4[1][2 * kd]
               + h01 * sv4[2][2 * kd]     + h11H * sv4[3][2 * kd];
      float v1 = h00 * sv4[0][2 * kd + 1] + h10H * sv4[1][2 * kd + 1]
               + h01 * sv4[2][2 * kd + 1] + h11H * sv4[3][2 * kd + 1];
      latu[t * 68 + kd] = bf_bits(v0) | (bf_bits(v1) << 16);
    }
  }
  __syncthreads();

  float wh0r[4], zhr[4], wmur[4], wsgr[4];
#pragma unroll
  for (int i = 0; i < 4; i++) {
    int u = w * 64 + i * 16 + col;
    wh0r[i] = wh0s[u]; zhr[i] = zhs[u];
    wmur[i] = wmus[LD + u]; wsgr[i] = wsgs[LD + u];
  }
  float wml[8], wsl[8];
#pragma unroll
  for (int q = 0; q < 8; q++) {
    wml[q] = wmus[col * 8 + q];
    wsl[q] = wsgs[col * 8 + q];
  }

  for (int mt = 0; mt < DPTS / 16; mt++) {
    short8 af[4];
#pragma unroll
    for (int ks = 0; ks < 4; ks++)
      af[ks] = *(const short8*)&latA[(mt * 16 + col) * 136 + ks * 32 + quad * 8];
    v4f acc[4];
#pragma unroll
    for (int i = 0; i < 4; i++) acc[i] = (v4f){0.f, 0.f, 0.f, 0.f};
#pragma unroll
    for (int i = 0; i < 4; i++)
#pragma unroll
      for (int ks = 0; ks < 4; ks++)
        acc[i] = __builtin_amdgcn_mfma_f32_16x16x32_bf16(
            af[ks], Breg[i][ks], acc[i], 0, 0, 0);

    float m4[4] = {0.f, 0.f, 0.f, 0.f}, s4[4] = {0.f, 0.f, 0.f, 0.f};
    float xr[4];
#pragma unroll
    for (int r = 0; r < 4; r++) xr[r] = xv[mt * 16 + quad * 4 + r];
#pragma unroll
    for (int i = 0; i < 4; i++)
#pragma unroll
      for (int r = 0; r < 4; r++) {
        float h = fmaxf(acc[i][r] + xr[r] * wh0r[i] + zhr[i], 0.f);
        m4[r] += h * wmur[i];
        s4[r] += h * wsgr[i];
      }
    if (w == 0) {
#pragma unroll
      for (int r = 0; r < 4; r++) {
        int t = mt * 16 + quad * 4 + r;
        uint4 lw = *(const uint4*)&latA[t * 136 + col * 8];
        float l0 = bf_lo(lw.x), l1 = bf_hi(lw.x), l2 = bf_lo(lw.y), l3 = bf_hi(lw.y);
        float l4 = bf_lo(lw.z), l5 = bf_hi(lw.z), l6 = bf_lo(lw.w), l7 = bf_hi(lw.w);
        m4[r] += l0 * wml[0] + l1 * wml[1] + l2 * wml[2] + l3 * wml[3]
               + l4 * wml[4] + l5 * wml[5] + l6 * wml[6] + l7 * wml[7];
        s4[r] += l0 * wsl[0] + l1 * wsl[1] + l2 * wsl[2] + l3 * wsl[3]
               + l4 * wsl[4] + l5 * wsl[5] + l6 * wsl[6] + l7 * wsl[7];
      }
    }
#pragma unroll
    for (int r = 0; r < 4; r++) {
#pragma unroll
      for (int m = 1; m <= 8; m <<= 1) {
        m4[r] += __shfl_xor(m4[r], m);
        s4[r] += __shfl_xor(s4[r], m);
      }
    }
    if (col == 0) {
#pragma unroll
      for (int r = 0; r < 4; r++) {
        int t = mt * 16 + quad * 4 + r;
        pmu[w][t] = m4[r];
        psg[w][t] = s4[r];
      }
    }
  }
  __syncthreads();

  if (j < DPTS) {
    float m  = (pmu[0][j] + pmu[1][j]) + (pmu[2][j] + pmu[3][j]) + bmu[0];
    float sv = (psg[0][j] + psg[1][j]) + (psg[2][j] + psg[3][j]) + bsig[0];
    out[(size_t)b * P_SZ + p0 + j] = m;
    float sp = (sv > 20.f) ? sv : log1pf(__expf(sv));
    out[(size_t)B_SZ * P_SZ + b * P_SZ + p0 + j] = 0.1f + 0.9f * sp;
  }
}

// ---------------------------------------------------------------------------
// Fused cooperative kernel: 256 blocks x 256 threads, 1 batch row per block.
// Stage (all) -> ODE on blocks 240..255 (4-wave fold of the verified MFMA
// ODE; dstate written via agent-scope RELEASE atomics) -> grid.sync ->
// decode both halves (dstate read via agent-scope ACQUIRE atomics).
// ---------------------------------------------------------------------------
struct OdeLds {
  float vL[OB][LD], kb0[OB][LD], kb1[OB][LD];
  short vinA[OB * 136];
  short h1A[OB * 264], h2A[OB * 264];
};
struct DecLds {
  short latA[DPTS * 136];
  float sv4[4][LD];
  float pmu[4][DPTS], psg[4][DPTS];
};
struct SharedMem {
  float xv[P_SZ], zr[LD];
  float zhs[HD], wh0s[HD];
  float wmus[384], wsgs[384];
  union { OdeLds ode; DecLds dec; } u;
};

__global__ __launch_bounds__(256) void fused_kernel(
    const float* __restrict__ x, const float* __restrict__ z,
    const float* __restrict__ x0,
    const float* __restrict__ W1, const float* __restrict__ b1,
    const float* __restrict__ b2, const float* __restrict__ b3,
    const float* __restrict__ Wh, const float* __restrict__ bh,
    const float* __restrict__ Wmu, const float* __restrict__ bmu,
    const float* __restrict__ Wsig, const float* __restrict__ bsig,
    float* __restrict__ out, float* __restrict__ dstate,
    const short8* __restrict__ W1Bs, const short8* __restrict__ W1hBs,
    const short8* __restrict__ W2Bs, const short8* __restrict__ W3Bs)
{
  __shared__ SharedMem smem;
  cg::grid_group grid = cg::this_grid();

  const int bid = blockIdx.x;
  const int j   = threadIdx.x;
  const int b   = bid;                 // this block's decode batch row
  const int w    = j >> 6;
  const int l    = j & 63;
  const int col  = l & 15;
  const int quad = l >> 4;

  // ---- P0: staging (all blocks) ----
  short8 Breg[4][4];                   // decode B-frags from raw Wh rows 1..128
#pragma unroll
  for (int i = 0; i < 4; i++)
#pragma unroll
    for (int ks = 0; ks < 4; ks++)
      Breg[i][ks] = pack_bfrag(Wh + HD, HD, ks * 32 + quad * 8,
                               (w * 4 + i) * 16 + col);

  smem.xv[j] = x[b * P_SZ + j];
  if (j < LD) smem.zr[j] = z[b * ZD + LD + j];
  smem.wh0s[j] = Wh[j];
  for (int idx = j; idx < 384; idx += 256) {
    smem.wmus[idx] = Wmu[idx];
    smem.wsgs[idx] = Wsig[idx];
  }
  __syncthreads();
  {
    float acc = bh[j];
#pragma unroll 8
    for (int k = 0; k < LD; k += 4) {
      float4 zv = *(const float4*)&smem.zr[k];
      acc += zv.x * Wh[(LD + 1 + k) * HD + j] + zv.y * Wh[(LD + 2 + k) * HD + j]
           + zv.z * Wh[(LD + 3 + k) * HD + j] + zv.w * Wh[(LD + 4 + k) * HD + j];
    }
    smem.zhs[j] = acc;
  }
  __syncthreads();

  const float tv0 = x0[0];
  const float tv1 = x[P_SZ - 1];
  const float H   = tv1 - tv0;

  // ---- P1: ODE on the last NODE blocks (4-wave fold, value-identical to
  // the 16-wave verified kernel) ----
  if (bid >= GRID_F - NODE) {
    OdeLds& O = smem.u.ode;
    const int b0 = (bid - (GRID_F - NODE)) * OB;
    unsigned int* vinU = (unsigned int*)O.vinA;
    for (int e = j; e < 1024; e += 256) {
      int r = e >> 6, kd = e & 63;
      O.vL[r][2 * kd]     = z[(b0 + r) * ZD + 2 * kd];
      O.vL[r][2 * kd + 1] = z[(b0 + r) * ZD + 2 * kd + 1];
      O.kb0[r][2 * kd] = 0.f; O.kb0[r][2 * kd + 1] = 0.f;
      float f0 = z[(b0 + r) * ZD + LD + 2 * kd];
      float f1 = z[(b0 + r) * ZD + LD + 2 * kd + 1];
      vinU[r * 68 + kd] = bf_bits(f0) | (bf_bits(f1) << 16);
    }
    __syncthreads();

    v4f c1r[4];
    {
      short8 afz[4];
#pragma unroll
      for (int ks = 0; ks < 4; ks++)
        afz[ks] = *(const short8*)&O.vinA[col * 136 + ks * 32 + quad * 8];
#pragma unroll
      for (int i = 0; i < 4; i++) {
        int nt = w * 4 + i;
        v4f a = (v4f){0.f, 0.f, 0.f, 0.f};
#pragma unroll
        for (int ks = 0; ks < 4; ks++)
          a = __builtin_amdgcn_mfma_f32_16x16x32_bf16(
              afz[ks], W1hBs[(nt * 4 + ks) * 64 + l], a, 0, 0, 0);
        float b1u = b1[nt * 16 + col];
#pragma unroll
        for (int r = 0; r < 4; r++) a[r] += b1u;
        c1r[i] = a;
      }
    }
    float w1tr[4], b2r[4], b3r[2];
#pragma unroll
    for (int i = 0; i < 4; i++) {
      w1tr[i] = W1[ZD * HD + (w * 4 + i) * 16 + col];
      b2r[i]  = b2[(w * 4 + i) * 16 + col];
    }
#pragma unroll
    for (int i3 = 0; i3 < 2; i3++) b3r[i3] = b3[(w * 2 + i3) * 16 + col];
    __syncthreads();

    auto eval_f = [&](float t, float (*vsrc)[LD], float (*kin)[LD], float c,
                      float (*kout)[LD]) {
      for (int e = j; e < 1024; e += 256) {
        int r = e >> 6, kd = e & 63;
        float v0 = vsrc[r][2 * kd]     + c * kin[r][2 * kd];
        float v1 = vsrc[r][2 * kd + 1] + c * kin[r][2 * kd + 1];
        vinU[r * 68 + kd] = bf_bits(v0) | (bf_bits(v1) << 16);
      }
      __syncthreads();
      {
        short8 a1[4];
#pragma unroll
        for (int ks = 0; ks < 4; ks++)
          a1[ks] = *(const short8*)&O.vinA[col * 136 + ks * 32 + quad * 8];
#pragma unroll
        for (int i = 0; i < 4; i++) {
          int nt = w * 4 + i;
          v4f acc = (v4f){0.f, 0.f, 0.f, 0.f};
#pragma unroll
          for (int ks = 0; ks < 4; ks++)
            acc = __builtin_amdgcn_mfma_f32_16x16x32_bf16(
                a1[ks], W1Bs[(nt * 4 + ks) * 64 + l], acc, 0, 0, 0);
          float tw = t * w1tr[i];
#pragma unroll
          for (int r = 0; r < 4; r++) {
            float h = fast_tanh(acc[r] + c1r[i][r] + tw);
            O.h1A[(quad * 4 + r) * 264 + nt * 16 + col] = (short)bf_bits(h);
          }
        }
      }
      __syncthreads();
      {
        short8 a2[8];
#pragma unroll
        for (int ks = 0; ks < 8; ks++)
          a2[ks] = *(const short8*)&O.h1A[col * 264 + ks * 32 + quad * 8];
#pragma unroll
        for (int i = 0; i < 4; i++) {
          int nt = w * 4 + i;
          v4f acc = (v4f){0.f, 0.f, 0.f, 0.f};
#pragma unroll
          for (int ks = 0; ks < 8; ks++)
            acc = __builtin_amdgcn_mfma_f32_16x16x32_bf16(
                a2[ks], W2Bs[(nt * 8 + ks) * 64 + l], acc, 0, 0, 0);
#pragma unroll
          for (int r = 0; r < 4; r++) {
            float h = fast_tanh(acc[r] + b2r[i]);
            O.h2A[(quad * 4 + r) * 264 + nt * 16 + col] = (short)bf_bits(h);
          }
        }
      }
      __syncthreads();
      {
        short8 a3[8];
#pragma unroll
        for (int ks = 0; ks < 8; ks++)
          a3[ks] = *(const short8*)&O.h2A[col * 264 + ks * 32 + quad * 8];
#pragma unroll
        for (int i3 = 0; i3 < 2; i3++) {
          int nt = w * 2 + i3;
          v4f acc = (v4f){0.f, 0.f, 0.f, 0.f};
#pragma unroll
          for (int ks = 0; ks < 8; ks++)
            acc = __builtin_amdgcn_mfma_f32_16x16x32_bf16(
                a3[ks], W3Bs[(nt * 8 + ks) * 64 + l], acc, 0, 0, 0);
#pragma unroll
          for (int r = 0; r < 4; r++)
            kout[quad * 4 + r][nt * 16 + col] = acc[r] + b3r[i3];
        }
      }
      __syncthreads();
    };

    eval_f(tv0, O.vL, O.kb0, 0.f, O.kb0);   // k1
    eval_f(tv1, O.vL, O.kb0, H,   O.kb1);   // k2

    // Heun + state write via agent-scope RELEASE atomics (8B pairs):
    // ull index u covers OB rows x 256 ull (512 floats) per row.
    unsigned long long* ds8 = (unsigned long long*)dstate;
    for (int e = j; e < OB * 256; e += 256) {
      int r = e >> 8, rem = e & 255, q = rem >> 6, m = rem & 63, k = 2 * m;
      float v0, v1;
      if (q == 0)      { v0 = O.vL[r][k];  v1 = O.vL[r][k + 1]; }
      else if (q == 1) { v0 = O.kb0[r][k]; v1 = O.kb0[r][k + 1]; }
      else if (q == 2) {
        v0 = O.vL[r][k]     + 0.5f * H * (O.kb0[r][k]     + O.kb1[r][k]);
        v1 = O.vL[r][k + 1] + 0.5f * H * (O.kb0[r][k + 1] + O.kb1[r][k + 1]);
      } else           { v0 = O.kb1[r][k]; v1 = O.kb1[r][k + 1]; }
      unsigned long long pv = (unsigned long long)__float_as_uint(v0)
                            | ((unsigned long long)__float_as_uint(v1) << 32);
      __hip_atomic_store(&ds8[(size_t)(b0 + r) * 256 + q * 64 + m], pv,
                         __ATOMIC_RELEASE, __HIP_MEMORY_SCOPE_AGENT);
    }
    __threadfence();
  }

  grid.sync();

  // ---- P2: decode, both halves ----
  DecLds& D = smem.u.dec;
  {
    // dstate read via agent-scope ACQUIRE atomics — architected coherent path
    const unsigned long long* ds8 = (const unsigned long long*)dstate;
    unsigned long long v = __hip_atomic_load(
        (unsigned long long*)&ds8[(size_t)b * 256 + j],
        __ATOMIC_ACQUIRE, __HIP_MEMORY_SCOPE_AGENT);
    int f = 2 * j;                       // float index 0..510 step 2
    D.sv4[f >> 7][f & 127]       = __uint_as_float((unsigned int)v);
    D.sv4[f >> 7][(f & 127) + 1] = __uint_as_float((unsigned int)(v >> 32));
  }
  __syncthreads();

  float wh0r[4], zhr[4], wmur[4], wsgr[4];
#pragma unroll
  for (int i = 0; i < 4; i++) {
    int u = w * 64 + i * 16 + col;
    wh0r[i] = smem.wh0s[u]; zhr[i] = smem.zhs[u];
    wmur[i] = smem.wmus[LD + u]; wsgr[i] = smem.wsgs[LD + u];
  }
  float wml[8], wsl[8];
#pragma unroll
  for (int q = 0; q < 8; q++) {
    wml[q] = smem.wmus[col * 8 + q];
    wsl[q] = smem.wsgs[col * 8 + q];
  }

  for (int half = 0; half < 2; half++) {
    const int p0 = half * DPTS;
    {
      const float invH = 1.0f / H;
      unsigned int* latu = (unsigned int*)D.latA;
      for (int idx = j; idx < DPTS * 64; idx += 256) {
        int t = idx >> 6, kd = idx & 63;
        float s  = (smem.xv[p0 + t] - tv0) * invH;
        float s2 = s * s, s3 = s2 * s;
        float h00 = 2.f * s3 - 3.f * s2 + 1.f;
        float h10H = (s3 - 2.f * s2 + s) * H;
        float h01 = 3.f * s2 - 2.f * s3;
        float h11H = (s3 - s2) * H;
        float v0 = h00 * D.sv4[0][2 * kd]     + h10H * D.sv4[1][2 * kd]
                 + h01 * D.sv4[2][2 * kd]     + h11H * D.sv4[3][2 * kd];
        float v1 = h00 * D.sv4[0][2 * kd + 1] + h10H * D.sv4[1][2 * kd + 1]
                 + h01 * D.sv4[2][2 * kd + 1] + h11H * D.sv4[3][2 * kd + 1];
        latu[t * 68 + kd] = bf_bits(v0) | (bf_bits(v1) << 16);
      }
    }
    __syncthreads();

    for (int mt = 0; mt < DPTS / 16; mt++) {
      short8 af[4];
#pragma unroll
      for (int ks = 0; ks < 4; ks++)
        af[ks] = *(const short8*)&D.latA[(mt * 16 + col) * 136 + ks * 32 + quad * 8];
      v4f acc[4];
#pragma unroll
      for (int i = 0; i < 4; i++) acc[i] = (v4f){0.f, 0.f, 0.f, 0.f};
#pragma unroll
      for (int i = 0; i < 4; i++)
#pragma unroll
        for (int ks = 0; ks < 4; ks++)
          acc[i] = __builtin_amdgcn_mfma_f32_16x16x32_bf16(
              af[ks], Breg[i][ks], acc[i], 0, 0, 0);

      float m4[4] = {0.f, 0.f, 0.f, 0.f}, s4[4] = {0.f, 0.f, 0.f, 0.f};
      float xr[4];
#pragma unroll
      for (int r = 0; r < 4; r++) xr[r] = smem.xv[p0 + mt * 16 + quad * 4 + r];
#pragma unroll
      for (int i = 0; i < 4; i++)
#pragma unroll
        for (int r = 0; r < 4; r++) {
          float h = fmaxf(acc[i][r] + xr[r] * wh0r[i] + zhr[i], 0.f);
          m4[r] += h * wmur[i];
          s4[r] += h * wsgr[i];
        }
      if (w == 0) {
#pragma unroll
        for (int r = 0; r < 4; r++) {
          int t = mt * 16 + quad * 4 + r;
          uint4 lw = *(const uint4*)&D.latA[t * 136 + col * 8];
          float l0 = bf_lo(lw.x), l1 = bf_hi(lw.x), l2 = bf_lo(lw.y), l3 = bf_hi(lw.y);
          float l4 = bf_lo(lw.z), l5 = bf_hi(lw.z), l6 = bf_lo(lw.w), l7 = bf_hi(lw.w);
          m4[r] += l0 * wml[0] + l1 * wml[1] + l2 * wml[2] + l3 * wml[3]
                 + l4 * wml[4] + l5 * wml[5] + l6 * wml[6] + l7 * wml[7];
          s4[r] += l0 * wsl[0] + l1 * wsl[1] + l2 * wsl[2] + l3 * wsl[3]
                 + l4 * wsl[4] + l5 * wsl[5] + l6 * wsl[6] + l7 * wsl[7];
        }
      }
#pragma unroll
      for (int r = 0; r < 4; r++) {
#pragma unroll
        for (int m = 1; m <= 8; m <<= 1) {
          m4[r] += __shfl_xor(m4[r], m);
          s4[r] += __shfl_xor(s4[r], m);
        }
      }
      if (col == 0) {
#pragma unroll
        for (int r = 0; r < 4; r++) {
          int t = mt * 16 + quad * 4 + r;
          D.pmu[w][t] = m4[r];
          D.psg[w][t] = s4[r];
        }
      }
    }
    __syncthreads();

    if (j < DPTS) {
      float m  = (D.pmu[0][j] + D.pmu[1][j]) + (D.pmu[2][j] + D.pmu[3][j]) + bmu[0];
      float sv = (D.psg[0][j] + D.psg[1][j]) + (D.psg[2][j] + D.psg[3][j]) + bsig[0];
      out[(size_t)b * P_SZ + p0 + j] = m;
      float sp = (sv > 20.f) ? sv : log1pf(__expf(sv));
      out[(size_t)B_SZ * P_SZ + b * P_SZ + p0 + j] = 0.1f + 0.9f * sp;
    }
    __syncthreads();   // latA/pmu reuse barrier before next half
  }
}

// ---------------------------------------------------------------------------
extern "C" void kernel_launch(void* const* d_in, const int* in_sizes, int n_in,
                              void* d_out, int out_size, void* d_ws, size_t ws_size,
                              hipStream_t stream) {
  const float* x    = (const float*)d_in[0];
  const float* z    = (const float*)d_in[1];
  const float* x0   = (const float*)d_in[2];
  const float* W1   = (const float*)d_in[3];
  const float* b1   = (const float*)d_in[4];
  const float* W2   = (const float*)d_in[5];
  const float* b2   = (const float*)d_in[6];
  const float* W3   = (const float*)d_in[7];
  const float* b3   = (const float*)d_in[8];
  const float* Wh   = (const float*)d_in[9];
  const float* bh   = (const float*)d_in[10];
  const float* Wmu  = (const float*)d_in[11];
  const float* bmu  = (const float*)d_in[12];
  const float* Wsig = (const float*)d_in[13];
  const float* bsig = (const float*)d_in[14];
  float* out = (float*)d_out;

  char* ws = (char*)d_ws;
  float* dstate = (float*)ws;                      // 512 KB
  uint4* W1B    = (uint4*)(ws + 524288);           //  64 KB
  uint4* W1hB   = (uint4*)(ws + 589824);           //  64 KB
  uint4* W2B    = (uint4*)(ws + 655360);           // 128 KB
  uint4* W3B    = (uint4*)(ws + 786432);           //  64 KB

  pack_kernel<<<dim3(80), dim3(256), 0, stream>>>(
      W1, W2, W3, W1B, W1hB, W2B, W3B);

  const short8* W1Bs  = (const short8*)W1B;
  const short8* W1hBs = (const short8*)W1hB;
  const short8* W2Bs  = (const short8*)W2B;
  const short8* W3Bs  = (const short8*)W3B;

  void* args[] = {
    (void*)&x, (void*)&z, (void*)&x0,
    (void*)&W1, (void*)&b1, (void*)&b2, (void*)&b3,
    (void*)&Wh, (void*)&bh,
    (void*)&Wmu, (void*)&bmu, (void*)&Wsig, (void*)&bsig,
    (void*)&out, (void*)&dstate,
    (void*)&W1Bs, (void*)&W1hBs, (void*)&W2Bs, (void*)&W3Bs
  };
  hipError_t rc = hipLaunchCooperativeKernel(
      (const void*)fused_kernel, dim3(GRID_F), dim3(256), args, 0, stream);

  if (rc != hipSuccess) {
    // Fallback: R2-verified two-kernel pipeline (pack already launched).
    ode_kernel<<<dim3(B_SZ / OB), dim3(1024), 0, stream>>>(
        x, z, x0, W1, b1, b2, b3, W1Bs, W1hBs, W2Bs, W3Bs, dstate);
    decode_kernel<<<dim3(P_SZ / DPTS, B_SZ), dim3(256), 0, stream>>>(
        x, x0, dstate, z, Wh, bh, Wmu, bmu, Wsig, bsig, out);
  }
}

// Round 7
// 121.798 us; speedup vs baseline: 1.7660x; 1.7660x over previous
//
#include <hip/hip_runtime.h>
#include <hip/hip_bf16.h>
#include <math.h>

// Problem dims (fixed by reference)
#define B_SZ 256
#define P_SZ 256
#define LD   128   // L_DIM (evolving part)
#define ZD   256   // Z_DIM
#define HD   256   // H_DIM
#define OB   16    // batch rows per ODE block (MFMA M dim)
#define DPTS 128   // points per decode block (2 blocks per row)
// Integrator: single Heun step over [x0, x[255]], 2 MLP evals total; Hermite
// right slope = predictor slope k2. absmax floor = bf16 latent quantization
// in decode (0.0078125) — bit-identical across all passing rounds.
//
// R7: cooperative fusion abandoned (R6: grid.sync machinery cost ~100 us).
// Two plain kernels:
//  K1 prep_ode (84 blocks x 1024 thr):
//    blocks 0..15  = MFMA ODE with IN-REGISTER self-pack of B-fragments from
//                    raw W1/W2 (numerics verified in R1; R1's 42 us was the
//                    compiler choosing VGPR=64 for 2-blocks/CU occupancy --
//                    fixed here with amdgpu_waves_per_eu(1,4) => 128-VGPR
//                    budget, deep gather pipelining) and W3 frags staged via
//                    LDS (keeps peak VGPR under budget).
//    blocks 16..79 = zh GEMV (R0 loop, bit-identical FMA order, 4 rows/blk).
//    blocks 80..83 = WhB pack (R0 mapping).
//    Roles independent -> no intra-kernel sync. Kernel boundary gives
//    coherence to K2.
//  K2 decode = R0-verified decode verbatim (packed WhB + precomputed zh).
// Saves one launch + gap + the pack kernel; zh/WhB hide under the ODE.

typedef __attribute__((ext_vector_type(8))) short short8;   // 8 bf16 = 4 VGPRs
typedef __attribute__((ext_vector_type(4))) float v4f;      // mfma C/D

__device__ __forceinline__ float fast_tanh(float v) {
  float e = __expf(2.0f * fabsf(v));
  float r = 1.0f - 2.0f / (e + 1.0f);
  return copysignf(r, v);
}

__device__ __forceinline__ unsigned int bf_bits(float f) {
  unsigned int u = __float_as_uint(f);
  return (u + 0x7fffu + ((u >> 16) & 1u)) >> 16;   // RNE
}
__device__ __forceinline__ float bf_lo(unsigned int u) {
  return __uint_as_float(u << 16);
}
__device__ __forceinline__ float bf_hi(unsigned int u) {
  return __uint_as_float(u & 0xffff0000u);
}

// Build one MFMA B-fragment in lane order: lane (col,quad) holds
// B[k = kb..kb+7][n], kb = ks*32 + quad*8, as 8 bf16 (RNE from f32).
__device__ __forceinline__ short8 pack_bfrag(const float* __restrict__ W,
                                             int stride, int kb, int n) {
  short8 r;
#pragma unroll
  for (int jj = 0; jj < 8; jj++)
    r[jj] = (short)bf_bits(W[(kb + jj) * stride + n]);
  return r;
}

// ---------------------------------------------------------------------------
// K1: prep_ode — heterogeneous block roles, 84 blocks x 1024 threads.
// ---------------------------------------------------------------------------
struct OdeL {
  float vL[OB][LD], kb0[OB][LD], kb1[OB][LD];   // 24 KB
  short vinA[OB * 136];                          // 4.25 KB
  short h1A[OB * 264], h2A[OB * 264];            // 16.5 KB
  short8 b3s[4096];                              // 64 KB (8 waves x 8 frags x 64 lanes)
};
struct ZhL { float zr[4][LD]; };
union PrepLds { OdeL ode; ZhL zh; };             // ~109 KB -> 1 block/CU

__global__ __launch_bounds__(1024)
__attribute__((amdgpu_waves_per_eu(1, 4)))
void prep_ode_kernel(
    const float* __restrict__ x, const float* __restrict__ z,
    const float* __restrict__ x0,
    const float* __restrict__ W1, const float* __restrict__ b1,
    const float* __restrict__ W2, const float* __restrict__ b2,
    const float* __restrict__ W3, const float* __restrict__ b3,
    const float* __restrict__ Wh, const float* __restrict__ bh,
    float* __restrict__ dstate, float* __restrict__ zh,
    uint4* __restrict__ WhB)
{
  __shared__ PrepLds s;
  const int bid = blockIdx.x;
  const int tid = threadIdx.x;

  if (bid >= 80) {
    // ---- WhB pack: Wh rows 1..128, f = ks*16+tt (R0 mapping) ----
    int i = (bid - 80) * 1024 + tid;             // 0..4095
    int l = i & 63, tt = (i >> 6) & 15, ks = i >> 10;
    int n = tt * 16 + (l & 15), kb = ks * 32 + ((l >> 4) & 3) * 8;
    const float* src = Wh + HD;                  // skip row 0
    uint4 o;
    o.x = bf_bits(src[(kb + 0) * HD + n]) | (bf_bits(src[(kb + 1) * HD + n]) << 16);
    o.y = bf_bits(src[(kb + 2) * HD + n]) | (bf_bits(src[(kb + 3) * HD + n]) << 16);
    o.z = bf_bits(src[(kb + 4) * HD + n]) | (bf_bits(src[(kb + 5) * HD + n]) << 16);
    o.w = bf_bits(src[(kb + 6) * HD + n]) | (bf_bits(src[(kb + 7) * HD + n]) << 16);
    WhB[i] = o;
    return;
  }

  if (bid >= 16) {
    // ---- zh: 4 rows per block; zh[b][j] = bh[j] + z[b,128:] @ Wh[129:257]
    // (identical FMA order to the R0-verified pack_zh loop) ----
    const int rb = (bid - 16) * 4;
    const int r = tid >> 8, j = tid & 255;
    if (j < LD) s.zh.zr[r][j] = z[(rb + r) * ZD + LD + j];
    __syncthreads();
    float acc = bh[j];
#pragma unroll 8
    for (int k = 0; k < LD; k += 4) {
      float4 zv = *(const float4*)&s.zh.zr[r][k];
      acc += zv.x * Wh[(LD + 1 + k) * HD + j] + zv.y * Wh[(LD + 2 + k) * HD + j]
           + zv.z * Wh[(LD + 3 + k) * HD + j] + zv.w * Wh[(LD + 4 + k) * HD + j];
    }
    zh[(rb + r) * HD + j] = acc;
    return;
  }

  // ======================= ODE (blocks 0..15) ==============================
  OdeL& O = s.ode;
  const int b0   = bid * OB;
  const int w    = tid >> 6;    // wave 0..15 = n-tile (layers 1/2)
  const int l    = tid & 63;
  const int col  = l & 15;
  const int quad = l >> 4;
  const int u12  = w * 16 + col;

  // ---- in-register B-fragment self-pack (issue gathers first) ----
  short8 B1fr[4], B2fr[8];
#pragma unroll
  for (int ks = 0; ks < 4; ks++)
    B1fr[ks] = pack_bfrag(W1, HD, ks * 32 + quad * 8, u12);
#pragma unroll
  for (int ks = 0; ks < 8; ks++)
    B2fr[ks] = pack_bfrag(W2, HD, ks * 32 + quad * 8, u12);
  if (w < 8) {   // W3 fragments -> LDS (keeps VGPR under the 128 budget)
#pragma unroll
    for (int ks = 0; ks < 8; ks++) {
      short8 f3 = pack_bfrag(W3, LD, ks * 32 + quad * 8, w * 16 + col);
      O.b3s[(w * 8 + ks) * 64 + l] = f3;
    }
  }

  {
    unsigned int* vinU = (unsigned int*)O.vinA;   // row stride 68 uints
    int r = tid >> 6, kd = tid & 63;              // 1024 = one elem pair each
    O.vL[r][2 * kd]     = z[(b0 + r) * ZD + 2 * kd];
    O.vL[r][2 * kd + 1] = z[(b0 + r) * ZD + 2 * kd + 1];
    O.kb0[r][2 * kd] = 0.f; O.kb0[r][2 * kd + 1] = 0.f;
    float f0 = z[(b0 + r) * ZD + LD + 2 * kd];
    float f1 = z[(b0 + r) * ZD + LD + 2 * kd + 1];
    vinU[r * 68 + kd] = bf_bits(f0) | (bf_bits(f1) << 16);
  }
  const float tv0 = x0[0];
  const float tv1 = x[P_SZ - 1];
  __syncthreads();

  // ---- c1r = zf @ W1[128:] + b1 (B1h gathered transiently here) ----
  v4f c1r = (v4f){0.f, 0.f, 0.f, 0.f};
  {
    short8 af[4];
#pragma unroll
    for (int ks = 0; ks < 4; ks++)
      af[ks] = *(const short8*)&O.vinA[col * 136 + ks * 32 + quad * 8];
#pragma unroll
    for (int ks = 0; ks < 4; ks++) {
      short8 b1h = pack_bfrag(W1, HD, 128 + ks * 32 + quad * 8, u12);
      c1r = __builtin_amdgcn_mfma_f32_16x16x32_bf16(af[ks], b1h, c1r, 0, 0, 0);
    }
  }
  {
    float b1u = b1[u12];
#pragma unroll
    for (int r = 0; r < 4; r++) c1r[r] += b1u;
  }
  const float w1tr = W1[ZD * HD + u12];
  const float b2r  = b2[u12];
  const float b3r  = (w < 8) ? b3[w * 16 + col] : 0.f;
  __syncthreads();   // c1 A-frag reads done before eval1 overwrites vinA

  auto eval_f = [&](float t, float (*vsrc)[LD], float (*kin)[LD], float c,
                    float (*kout)[LD]) {
    {
      unsigned int* vinU = (unsigned int*)O.vinA;
      int r = tid >> 6, kd = tid & 63;
      float v0 = vsrc[r][2 * kd]     + c * kin[r][2 * kd];
      float v1 = vsrc[r][2 * kd + 1] + c * kin[r][2 * kd + 1];
      vinU[r * 68 + kd] = bf_bits(v0) | (bf_bits(v1) << 16);
    }
    __syncthreads();
    // layer 1: (16x128)@(128x256), + c1 + t*w1t, tanh -> h1A ; n-tile = w
    {
      short8 a1[4];
#pragma unroll
      for (int ks = 0; ks < 4; ks++)
        a1[ks] = *(const short8*)&O.vinA[col * 136 + ks * 32 + quad * 8];
      v4f acc = (v4f){0.f, 0.f, 0.f, 0.f};
#pragma unroll
      for (int ks = 0; ks < 4; ks++)
        acc = __builtin_amdgcn_mfma_f32_16x16x32_bf16(a1[ks], B1fr[ks], acc, 0, 0, 0);
      float tw = t * w1tr;
#pragma unroll
      for (int r = 0; r < 4; r++) {
        float h = fast_tanh(acc[r] + c1r[r] + tw);
        O.h1A[(quad * 4 + r) * 264 + u12] = (short)bf_bits(h);
      }
    }
    __syncthreads();
    // layer 2: (16x256)@(256x256), + b2, tanh -> h2A ; n-tile = w
    {
      short8 a2[8];
#pragma unroll
      for (int ks = 0; ks < 8; ks++)
        a2[ks] = *(const short8*)&O.h1A[col * 264 + ks * 32 + quad * 8];
      v4f acc = (v4f){0.f, 0.f, 0.f, 0.f};
#pragma unroll
      for (int ks = 0; ks < 8; ks++)
        acc = __builtin_amdgcn_mfma_f32_16x16x32_bf16(a2[ks], B2fr[ks], acc, 0, 0, 0);
#pragma unroll
      for (int r = 0; r < 4; r++) {
        float h = fast_tanh(acc[r] + b2r);
        O.h2A[(quad * 4 + r) * 264 + u12] = (short)bf_bits(h);
      }
    }
    __syncthreads();
    // layer 3: (16x256)@(256x128), + b3 -> kout (fp32 LDS); waves 0..7,
    // B-frags from LDS (b3s)
    if (w < 8) {
      short8 a3[8];
#pragma unroll
      for (int ks = 0; ks < 8; ks++)
        a3[ks] = *(const short8*)&O.h2A[col * 264 + ks * 32 + quad * 8];
      v4f acc = (v4f){0.f, 0.f, 0.f, 0.f};
#pragma unroll
      for (int ks = 0; ks < 8; ks++)
        acc = __builtin_amdgcn_mfma_f32_16x16x32_bf16(
            a3[ks], O.b3s[(w * 8 + ks) * 64 + l], acc, 0, 0, 0);
      int u = w * 16 + col;
#pragma unroll
      for (int r = 0; r < 4; r++)
        kout[quad * 4 + r][u] = acc[r] + b3r;
    }
    __syncthreads();
  };

  const float H = tv1 - tv0;
  eval_f(tv0, O.vL, O.kb0, 0.f, O.kb0);   // k1 = f(t0, vL)
  eval_f(tv1, O.vL, O.kb0, H,   O.kb1);   // k2 = f(t1, vL + H*k1)

  // Heun corrector fused into the state write (2 elems per thread)
  {
    int idx = tid;
#pragma unroll
    for (int it = 0; it < 2; it++, idx += 1024) {
      int r = idx >> 7, k = idx & 127;
      float vl = O.vL[r][k], k0 = O.kb0[r][k], k1v = O.kb1[r][k];
      float vn = vl + 0.5f * H * (k0 + k1v);
      size_t base = (size_t)(b0 + r) * 512 + k;
      dstate[base]       = vl;
      dstate[base + 128] = k0;
      dstate[base + 256] = vn;
      dstate[base + 384] = k1v;       // predictor slope as Hermite right slope
    }
  }
}

// ---------------------------------------------------------------------------
// K2: decode — R0-verified form verbatim (packed WhB + precomputed zh).
// Block = (half, b): 512 blocks x 256 threads, 128 points each.
// ---------------------------------------------------------------------------
__global__ __launch_bounds__(256, 2) void decode_kernel(
    const float* __restrict__ x, const float* __restrict__ x0,
    const float* __restrict__ dstate,
    const float* __restrict__ zh, const float* __restrict__ Wh,
    const short8* __restrict__ WhB,
    const float* __restrict__ Wmu, const float* __restrict__ bmu,
    const float* __restrict__ Wsig, const float* __restrict__ bsig,
    float* __restrict__ out)
{
  const int b  = blockIdx.y;
  const int p0 = blockIdx.x * DPTS;   // half 0 or 1
  const int j  = threadIdx.x;

  __shared__ short latA[DPTS * 136];   // 128 points x 128 bf16 (+pad)
  __shared__ float sv4[4][LD];
  __shared__ float xv[DPTS];
  __shared__ float zhs[HD], wh0s[HD];
  __shared__ float wmus[384], wsgs[384];
  __shared__ float pmu[4][DPTS], psg[4][DPTS];

  for (int idx = j; idx < 512; idx += 256)
    sv4[idx >> 7][idx & 127] = dstate[(size_t)b * 512 + idx];
  if (j < DPTS) xv[j] = x[b * P_SZ + p0 + j];
  zhs[j]  = zh[b * HD + j];
  wh0s[j] = Wh[j];
  for (int idx = j; idx < 384; idx += 256) {
    wmus[idx] = Wmu[idx];
    wsgs[idx] = Wsig[idx];
  }
  __syncthreads();

  // Hermite over the single macro span [x0, x[255]]
  {
    const float t0 = x0[0];
    const float t1 = x[b * P_SZ + P_SZ - 1];
    const float H = t1 - t0, invH = 1.0f / H;
    unsigned int* latu = (unsigned int*)latA;   // row stride 68 uints
    for (int idx = j; idx < DPTS * 64; idx += 256) {
      int t = idx >> 6, kd = idx & 63;
      float s  = (xv[t] - t0) * invH;
      float s2 = s * s, s3 = s2 * s;
      float h00 = 2.f * s3 - 3.f * s2 + 1.f;
      float h10H = (s3 - 2.f * s2 + s) * H;
      float h01 = 3.f * s2 - 2.f * s3;
      float h11H = (s3 - s2) * H;
      float v0 = h00 * sv4[0][2 * kd]     + h10H * sv4[1][2 * kd]
               + h01 * sv4[2][2 * kd]     + h11H * sv4[3][2 * kd];
      float v1 = h00 * sv4[0][2 * kd + 1] + h10H * sv4[1][2 * kd + 1]
               + h01 * sv4[2][2 * kd + 1] + h11H * sv4[3][2 * kd + 1];
      latu[t * 68 + kd] = bf_bits(v0) | (bf_bits(v1) << 16);
    }
  }
  __syncthreads();

  const int w    = j >> 6;    // wave: n-tiles w*4 .. w*4+3 (units w*64..w*64+63)
  const int l    = j & 63;
  const int col  = l & 15;
  const int quad = l >> 4;

  // B-fragments register-resident (loaded once, reused for all 8 m-tiles)
  short8 Breg[4][4];
#pragma unroll
  for (int i = 0; i < 4; i++)
#pragma unroll
    for (int ks = 0; ks < 4; ks++)
      Breg[i][ks] = WhB[(ks * 16 + (w * 4 + i)) * 64 + l];

  float wh0r[4], zhr[4], wmur[4], wsgr[4];
#pragma unroll
  for (int i = 0; i < 4; i++) {
    int u = w * 64 + i * 16 + col;
    wh0r[i] = wh0s[u]; zhr[i] = zhs[u];
    wmur[i] = wmus[LD + u]; wsgr[i] = wsgs[LD + u];
  }
  float wml[8], wsl[8];
#pragma unroll
  for (int q = 0; q < 8; q++) {
    wml[q] = wmus[col * 8 + q];
    wsl[q] = wsgs[col * 8 + q];
  }

  for (int mt = 0; mt < DPTS / 16; mt++) {   // 8 m-tiles of 16 points
    short8 af[4];
#pragma unroll
    for (int ks = 0; ks < 4; ks++)
      af[ks] = *(const short8*)&latA[(mt * 16 + col) * 136 + ks * 32 + quad * 8];
    v4f acc[4];
#pragma unroll
    for (int i = 0; i < 4; i++) acc[i] = (v4f){0.f, 0.f, 0.f, 0.f};
#pragma unroll
    for (int i = 0; i < 4; i++)
#pragma unroll
      for (int ks = 0; ks < 4; ks++)
        acc[i] = __builtin_amdgcn_mfma_f32_16x16x32_bf16(
            af[ks], Breg[i][ks], acc[i], 0, 0, 0);

    float m4[4] = {0.f, 0.f, 0.f, 0.f}, s4[4] = {0.f, 0.f, 0.f, 0.f};
    float xr[4];
#pragma unroll
    for (int r = 0; r < 4; r++) xr[r] = xv[mt * 16 + quad * 4 + r];
#pragma unroll
    for (int i = 0; i < 4; i++)
#pragma unroll
      for (int r = 0; r < 4; r++) {
        float h = fmaxf(acc[i][r] + xr[r] * wh0r[i] + zhr[i], 0.f);
        m4[r] += h * wmur[i];
        s4[r] += h * wsgr[i];
      }
    if (w == 0) {   // latent-direct term added exactly once
#pragma unroll
      for (int r = 0; r < 4; r++) {
        int t = mt * 16 + quad * 4 + r;
        uint4 lw = *(const uint4*)&latA[t * 136 + col * 8];
        float l0 = bf_lo(lw.x), l1 = bf_hi(lw.x), l2 = bf_lo(lw.y), l3 = bf_hi(lw.y);
        float l4 = bf_lo(lw.z), l5 = bf_hi(lw.z), l6 = bf_lo(lw.w), l7 = bf_hi(lw.w);
        m4[r] += l0 * wml[0] + l1 * wml[1] + l2 * wml[2] + l3 * wml[3]
               + l4 * wml[4] + l5 * wml[5] + l6 * wml[6] + l7 * wml[7];
        s4[r] += l0 * wsl[0] + l1 * wsl[1] + l2 * wsl[2] + l3 * wsl[3]
               + l4 * wsl[4] + l5 * wsl[5] + l6 * wsl[6] + l7 * wsl[7];
      }
    }
#pragma unroll
    for (int r = 0; r < 4; r++) {
#pragma unroll
      for (int m = 1; m <= 8; m <<= 1) {
        m4[r] += __shfl_xor(m4[r], m);
        s4[r] += __shfl_xor(s4[r], m);
      }
    }
    if (col == 0) {
#pragma unroll
      for (int r = 0; r < 4; r++) {
        int t = mt * 16 + quad * 4 + r;
        pmu[w][t] = m4[r];
        psg[w][t] = s4[r];
      }
    }
  }
  __syncthreads();

  if (j < DPTS) {
    float m  = (pmu[0][j] + pmu[1][j]) + (pmu[2][j] + pmu[3][j]) + bmu[0];
    float sv = (psg[0][j] + psg[1][j]) + (psg[2][j] + psg[3][j]) + bsig[0];
    out[(size_t)b * P_SZ + p0 + j] = m;
    float sp = (sv > 20.f) ? sv : log1pf(__expf(sv));
    out[(size_t)B_SZ * P_SZ + b * P_SZ + p0 + j] = 0.1f + 0.9f * sp;
  }
}

// ---------------------------------------------------------------------------
extern "C" void kernel_launch(void* const* d_in, const int* in_sizes, int n_in,
                              void* d_out, int out_size, void* d_ws, size_t ws_size,
                              hipStream_t stream) {
  const float* x    = (const float*)d_in[0];
  const float* z    = (const float*)d_in[1];
  const float* x0   = (const float*)d_in[2];
  const float* W1   = (const float*)d_in[3];
  const float* b1   = (const float*)d_in[4];
  const float* W2   = (const float*)d_in[5];
  const float* b2   = (const float*)d_in[6];
  const float* W3   = (const float*)d_in[7];
  const float* b3   = (const float*)d_in[8];
  const float* Wh   = (const float*)d_in[9];
  const float* bh   = (const float*)d_in[10];
  const float* Wmu  = (const float*)d_in[11];
  const float* bmu  = (const float*)d_in[12];
  const float* Wsig = (const float*)d_in[13];
  const float* bsig = (const float*)d_in[14];
  float* out = (float*)d_out;

  char* ws = (char*)d_ws;
  float* zh     = (float*)ws;                      //  0       256 KB
  float* dstate = (float*)(ws + 262144);           // +256 KB  512 KB
  uint4* WhB    = (uint4*)(ws + 786432);           //           64 KB

  prep_ode_kernel<<<dim3(84), dim3(1024), 0, stream>>>(
      x, z, x0, W1, b1, W2, b2, W3, b3, Wh, bh, dstate, zh, WhB);
  decode_kernel<<<dim3(P_SZ / DPTS, B_SZ), dim3(256), 0, stream>>>(
      x, x0, dstate, zh, Wh, (const short8*)WhB, Wmu, bmu, Wsig, bsig, out);
}

// Round 8
// 112.636 us; speedup vs baseline: 1.9096x; 1.0813x over previous
//
#include <hip/hip_runtime.h>
#include <hip/hip_bf16.h>
#include <math.h>

// Problem dims (fixed by reference)
#define B_SZ 256
#define P_SZ 256
#define LD   128   // L_DIM (evolving part)
#define ZD   256   // Z_DIM
#define HD   256   // H_DIM
#define OB   16    // batch rows per ODE block (MFMA M dim)
#define DPTS 128   // points per decode block (2 blocks per row)
// Integrator: single Heun step over [x0, x[255]], 2 MLP evals total; Hermite
// right slope = predictor slope k2. absmax floor = bf16 latent quantization
// in decode (0.0078125) — bit-identical across all passing rounds.
//
// R8: recombination of ONLY verified pieces, ordered for overlap.
//  L1 pack_kernel (80 blk)      = R2-verified: W1B/W1hB/W2B/W3B (the only
//                                 true dependency of the ODE).
//  L2 ode_plus (84 blk x 1024)  = blocks 0..15: R2-verified MFMA ODE
//                                 (packed frags, B1/B2 reg-hoisted);
//                                 blocks 16..79: R7-verified zh GEMV;
//                                 blocks 80..83: R7-verified WhB pack.
//                                 zh/WhB (decode-only inputs) now run on CUs
//                                 the 16-block ODE leaves idle instead of
//                                 serializing before it (R0's 352-blk pack).
//  L3 decode (512 blk)          = R0-verified verbatim.
// vs R0: launch-1 is 80 not 352 blocks; zh+WhB hidden under the ODE.
// No numeric change anywhere.

typedef __attribute__((ext_vector_type(8))) short short8;   // 8 bf16 = 4 VGPRs
typedef __attribute__((ext_vector_type(4))) float v4f;      // mfma C/D

__device__ __forceinline__ float fast_tanh(float v) {
  float e = __expf(2.0f * fabsf(v));
  float r = 1.0f - 2.0f / (e + 1.0f);
  return copysignf(r, v);
}

__device__ __forceinline__ unsigned int bf_bits(float f) {
  unsigned int u = __float_as_uint(f);
  return (u + 0x7fffu + ((u >> 16) & 1u)) >> 16;   // RNE
}
__device__ __forceinline__ float bf_lo(unsigned int u) {
  return __uint_as_float(u << 16);
}
__device__ __forceinline__ float bf_hi(unsigned int u) {
  return __uint_as_float(u & 0xffff0000u);
}

// ---------------------------------------------------------------------------
// L1: pack ODE weights into MFMA B-fragment lane order (R2-verified).
// ---------------------------------------------------------------------------
__global__ __launch_bounds__(256) void pack_kernel(
    const float* __restrict__ W1, const float* __restrict__ W2,
    const float* __restrict__ W3,
    uint4* __restrict__ W1B, uint4* __restrict__ W1hB,
    uint4* __restrict__ W2B, uint4* __restrict__ W3B)
{
  int idx = blockIdx.x * 256 + threadIdx.x;
  const float* src; int stride, kb, n; uint4* dst; int di;
  if (idx < 4096) {            // W1B: K=128, N=256, f = nt*4+ks
    int i = idx, l = i & 63, f = i >> 6;
    int ks = f & 3, nt = f >> 2;
    n = nt * 16 + (l & 15); kb = ks * 32 + (l >> 4) * 8;
    src = W1; stride = HD; dst = W1B; di = i;
  } else if (idx < 8192) {     // W1hB: W1 rows 128..255
    int i = idx - 4096, l = i & 63, f = i >> 6;
    int ks = f & 3, nt = f >> 2;
    n = nt * 16 + (l & 15); kb = 128 + ks * 32 + (l >> 4) * 8;
    src = W1; stride = HD; dst = W1hB; di = i;
  } else if (idx < 16384) {    // W2B: K=256, N=256, f = nt*8+ks
    int i = idx - 8192, l = i & 63, f = i >> 6;
    int ks = f & 7, nt = f >> 3;
    n = nt * 16 + (l & 15); kb = ks * 32 + (l >> 4) * 8;
    src = W2; stride = HD; dst = W2B; di = i;
  } else {                     // W3B: K=256, N=128, f = nt*8+ks
    int i = idx - 16384, l = i & 63, f = i >> 6;
    int ks = f & 7, nt = f >> 3;
    n = nt * 16 + (l & 15); kb = ks * 32 + (l >> 4) * 8;
    src = W3; stride = LD; dst = W3B; di = i;
  }
  uint4 o;
  o.x = bf_bits(src[(kb + 0) * stride + n]) | (bf_bits(src[(kb + 1) * stride + n]) << 16);
  o.y = bf_bits(src[(kb + 2) * stride + n]) | (bf_bits(src[(kb + 3) * stride + n]) << 16);
  o.z = bf_bits(src[(kb + 4) * stride + n]) | (bf_bits(src[(kb + 5) * stride + n]) << 16);
  o.w = bf_bits(src[(kb + 6) * stride + n]) | (bf_bits(src[(kb + 7) * stride + n]) << 16);
  dst[di] = o;
}

// ---------------------------------------------------------------------------
// L2: ode_plus — 84 blocks x 1024 threads, heterogeneous roles.
//   0..15  : R2-verified MFMA ODE (reads packed W*B)
//   16..79 : zh GEMV (R7-verified; bit-identical FMA order to R0)
//   80..83 : WhB pack (R7-verified)
// ---------------------------------------------------------------------------
struct OdeL {
  float vL[OB][LD], kb0[OB][LD], kb1[OB][LD];   // 24 KB
  short vinA[OB * 136];                          // 4.25 KB
  short h1A[OB * 264], h2A[OB * 264];            // 16.5 KB
};
struct ZhL { float zr[4][LD]; };
union PrepLds { OdeL ode; ZhL zh; };

__global__ __launch_bounds__(1024, 1) void ode_plus_kernel(
    const float* __restrict__ x, const float* __restrict__ z,
    const float* __restrict__ x0,
    const float* __restrict__ W1, const float* __restrict__ b1,
    const float* __restrict__ b2, const float* __restrict__ b3,
    const float* __restrict__ Wh, const float* __restrict__ bh,
    const short8* __restrict__ W1B, const short8* __restrict__ W1hB,
    const short8* __restrict__ W2B, const short8* __restrict__ W3B,
    float* __restrict__ dstate, float* __restrict__ zh,
    uint4* __restrict__ WhB)
{
  __shared__ PrepLds s;
  const int bid = blockIdx.x;
  const int tid = threadIdx.x;

  if (bid >= 80) {
    // ---- WhB pack: Wh rows 1..128, f = ks*16+tt (R0 mapping; R7-verified)
    int i = (bid - 80) * 1024 + tid;             // 0..4095
    int l = i & 63, tt = (i >> 6) & 15, ks = i >> 10;
    int n = tt * 16 + (l & 15), kb = ks * 32 + ((l >> 4) & 3) * 8;
    const float* src = Wh + HD;                  // skip row 0
    uint4 o;
    o.x = bf_bits(src[(kb + 0) * HD + n]) | (bf_bits(src[(kb + 1) * HD + n]) << 16);
    o.y = bf_bits(src[(kb + 2) * HD + n]) | (bf_bits(src[(kb + 3) * HD + n]) << 16);
    o.z = bf_bits(src[(kb + 4) * HD + n]) | (bf_bits(src[(kb + 5) * HD + n]) << 16);
    o.w = bf_bits(src[(kb + 6) * HD + n]) | (bf_bits(src[(kb + 7) * HD + n]) << 16);
    WhB[i] = o;
    return;
  }

  if (bid >= 16) {
    // ---- zh: 4 rows/block; zh[b][j] = bh[j] + z[b,128:] @ Wh[129:257]
    // (identical FMA order to the R0-verified loop; R7-verified)
    const int rb = (bid - 16) * 4;
    const int r = tid >> 8, j = tid & 255;
    if (j < LD) s.zh.zr[r][j] = z[(rb + r) * ZD + LD + j];
    __syncthreads();
    float acc = bh[j];
#pragma unroll 8
    for (int k = 0; k < LD; k += 4) {
      float4 zv = *(const float4*)&s.zh.zr[r][k];
      acc += zv.x * Wh[(LD + 1 + k) * HD + j] + zv.y * Wh[(LD + 2 + k) * HD + j]
           + zv.z * Wh[(LD + 3 + k) * HD + j] + zv.w * Wh[(LD + 4 + k) * HD + j];
    }
    zh[(rb + r) * HD + j] = acc;
    return;
  }

  // ======================= ODE (blocks 0..15, R2-verified) =================
  OdeL& O = s.ode;
  const int b0   = bid * OB;
  const int w    = tid >> 6;    // wave 0..15 = n-tile (layers 1/2)
  const int l    = tid & 63;
  const int col  = l & 15;
  const int quad = l >> 4;
  const int u12  = w * 16 + col;

  // Register-resident B-fragments for layers 1/2 (coalesced; prefetch under
  // the z staging + c1 phase). 48 VGPRs.
  short8 B1fr[4], B2fr[8];
#pragma unroll
  for (int ks = 0; ks < 4; ks++) B1fr[ks] = W1B[(w * 4 + ks) * 64 + l];
#pragma unroll
  for (int ks = 0; ks < 8; ks++) B2fr[ks] = W2B[(w * 8 + ks) * 64 + l];

  {
    unsigned int* vinU = (unsigned int*)O.vinA;   // row stride 68 uints
    int r = tid >> 6, kd = tid & 63;              // one elem pair per thread
    O.vL[r][2 * kd]     = z[(b0 + r) * ZD + 2 * kd];
    O.vL[r][2 * kd + 1] = z[(b0 + r) * ZD + 2 * kd + 1];
    O.kb0[r][2 * kd] = 0.f; O.kb0[r][2 * kd + 1] = 0.f;
    float f0 = z[(b0 + r) * ZD + LD + 2 * kd];
    float f1 = z[(b0 + r) * ZD + LD + 2 * kd + 1];
    vinU[r * 68 + kd] = bf_bits(f0) | (bf_bits(f1) << 16);
  }
  const float tv0 = x0[0];
  const float tv1 = x[P_SZ - 1];
  __syncthreads();

  // ---- c1r = zf @ W1[128:] + b1 for n-tile w ----
  v4f c1r = (v4f){0.f, 0.f, 0.f, 0.f};
  {
    short8 af[4];
#pragma unroll
    for (int ks = 0; ks < 4; ks++)
      af[ks] = *(const short8*)&O.vinA[col * 136 + ks * 32 + quad * 8];
#pragma unroll
    for (int ks = 0; ks < 4; ks++)
      c1r = __builtin_amdgcn_mfma_f32_16x16x32_bf16(
          af[ks], W1hB[(w * 4 + ks) * 64 + l], c1r, 0, 0, 0);
  }
  {
    float b1u = b1[u12];
#pragma unroll
    for (int r = 0; r < 4; r++) c1r[r] += b1u;
  }
  const float w1tr = W1[ZD * HD + u12];
  const float b2r  = b2[u12];
  const float b3r  = (w < 8) ? b3[w * 16 + col] : 0.f;
  __syncthreads();   // c1 A-frag reads done before eval1 overwrites vinA

  auto eval_f = [&](float t, float (*vsrc)[LD], float (*kin)[LD], float c,
                    float (*kout)[LD]) {
    {
      unsigned int* vinU = (unsigned int*)O.vinA;
      int r = tid >> 6, kd = tid & 63;
      float v0 = vsrc[r][2 * kd]     + c * kin[r][2 * kd];
      float v1 = vsrc[r][2 * kd + 1] + c * kin[r][2 * kd + 1];
      vinU[r * 68 + kd] = bf_bits(v0) | (bf_bits(v1) << 16);
    }
    __syncthreads();
    // layer 1: (16x128)@(128x256), + c1 + t*w1t, tanh -> h1A ; n-tile = w
    {
      short8 a1[4];
#pragma unroll
      for (int ks = 0; ks < 4; ks++)
        a1[ks] = *(const short8*)&O.vinA[col * 136 + ks * 32 + quad * 8];
      v4f acc = (v4f){0.f, 0.f, 0.f, 0.f};
#pragma unroll
      for (int ks = 0; ks < 4; ks++)
        acc = __builtin_amdgcn_mfma_f32_16x16x32_bf16(a1[ks], B1fr[ks], acc, 0, 0, 0);
      float tw = t * w1tr;
#pragma unroll
      for (int r = 0; r < 4; r++) {
        float h = fast_tanh(acc[r] + c1r[r] + tw);
        O.h1A[(quad * 4 + r) * 264 + u12] = (short)bf_bits(h);
      }
    }
    __syncthreads();
    // layer 2: (16x256)@(256x256), + b2, tanh -> h2A ; n-tile = w
    {
      short8 a2[8];
#pragma unroll
      for (int ks = 0; ks < 8; ks++)
        a2[ks] = *(const short8*)&O.h1A[col * 264 + ks * 32 + quad * 8];
      v4f acc = (v4f){0.f, 0.f, 0.f, 0.f};
#pragma unroll
      for (int ks = 0; ks < 8; ks++)
        acc = __builtin_amdgcn_mfma_f32_16x16x32_bf16(a2[ks], B2fr[ks], acc, 0, 0, 0);
#pragma unroll
      for (int r = 0; r < 4; r++) {
        float h = fast_tanh(acc[r] + b2r);
        O.h2A[(quad * 4 + r) * 264 + u12] = (short)bf_bits(h);
      }
    }
    __syncthreads();
    // layer 3: (16x256)@(256x128), + b3 -> kout (fp32 LDS); waves 0..7
    if (w < 8) {
      short8 a3[8];
#pragma unroll
      for (int ks = 0; ks < 8; ks++)
        a3[ks] = *(const short8*)&O.h2A[col * 264 + ks * 32 + quad * 8];
      v4f acc = (v4f){0.f, 0.f, 0.f, 0.f};
#pragma unroll
      for (int ks = 0; ks < 8; ks++)
        acc = __builtin_amdgcn_mfma_f32_16x16x32_bf16(
            a3[ks], W3B[(w * 8 + ks) * 64 + l], acc, 0, 0, 0);
      int u = w * 16 + col;
#pragma unroll
      for (int r = 0; r < 4; r++)
        kout[quad * 4 + r][u] = acc[r] + b3r;
    }
    __syncthreads();
  };

  const float H = tv1 - tv0;
  eval_f(tv0, O.vL, O.kb0, 0.f, O.kb0);   // k1 = f(t0, vL)
  eval_f(tv1, O.vL, O.kb0, H,   O.kb1);   // k2 = f(t1, vL + H*k1)

  // Heun corrector fused into the state write (2 elems per thread)
  {
    int idx = tid;
#pragma unroll
    for (int it = 0; it < 2; it++, idx += 1024) {
      int r = idx >> 7, k = idx & 127;
      float vl = O.vL[r][k], k0 = O.kb0[r][k], k1v = O.kb1[r][k];
      float vn = vl + 0.5f * H * (k0 + k1v);
      size_t base = (size_t)(b0 + r) * 512 + k;
      dstate[base]       = vl;
      dstate[base + 128] = k0;
      dstate[base + 256] = vn;
      dstate[base + 384] = k1v;       // predictor slope as Hermite right slope
    }
  }
}

// ---------------------------------------------------------------------------
// L3: decode — R0-verified form verbatim (packed WhB + precomputed zh).
// Block = (half, b): 512 blocks x 256 threads, 128 points each.
// ---------------------------------------------------------------------------
__global__ __launch_bounds__(256, 2) void decode_kernel(
    const float* __restrict__ x, const float* __restrict__ x0,
    const float* __restrict__ dstate,
    const float* __restrict__ zh, const float* __restrict__ Wh,
    const short8* __restrict__ WhB,
    const float* __restrict__ Wmu, const float* __restrict__ bmu,
    const float* __restrict__ Wsig, const float* __restrict__ bsig,
    float* __restrict__ out)
{
  const int b  = blockIdx.y;
  const int p0 = blockIdx.x * DPTS;   // half 0 or 1
  const int j  = threadIdx.x;

  __shared__ short latA[DPTS * 136];   // 128 points x 128 bf16 (+pad)
  __shared__ float sv4[4][LD];
  __shared__ float xv[DPTS];
  __shared__ float zhs[HD], wh0s[HD];
  __shared__ float wmus[384], wsgs[384];
  __shared__ float pmu[4][DPTS], psg[4][DPTS];

  for (int idx = j; idx < 512; idx += 256)
    sv4[idx >> 7][idx & 127] = dstate[(size_t)b * 512 + idx];
  if (j < DPTS) xv[j] = x[b * P_SZ + p0 + j];
  zhs[j]  = zh[b * HD + j];
  wh0s[j] = Wh[j];
  for (int idx = j; idx < 384; idx += 256) {
    wmus[idx] = Wmu[idx];
    wsgs[idx] = Wsig[idx];
  }
  __syncthreads();

  // Hermite over the single macro span [x0, x[255]]
  {
    const float t0 = x0[0];
    const float t1 = x[b * P_SZ + P_SZ - 1];
    const float H = t1 - t0, invH = 1.0f / H;
    unsigned int* latu = (unsigned int*)latA;   // row stride 68 uints
    for (int idx = j; idx < DPTS * 64; idx += 256) {
      int t = idx >> 6, kd = idx & 63;
      float s  = (xv[t] - t0) * invH;
      float s2 = s * s, s3 = s2 * s;
      float h00 = 2.f * s3 - 3.f * s2 + 1.f;
      float h10H = (s3 - 2.f * s2 + s) * H;
      float h01 = 3.f * s2 - 2.f * s3;
      float h11H = (s3 - s2) * H;
      float v0 = h00 * sv4[0][2 * kd]     + h10H * sv4[1][2 * kd]
               + h01 * sv4[2][2 * kd]     + h11H * sv4[3][2 * kd];
      float v1 = h00 * sv4[0][2 * kd + 1] + h10H * sv4[1][2 * kd + 1]
               + h01 * sv4[2][2 * kd + 1] + h11H * sv4[3][2 * kd + 1];
      latu[t * 68 + kd] = bf_bits(v0) | (bf_bits(v1) << 16);
    }
  }
  __syncthreads();

  const int w    = j >> 6;    // wave: n-tiles w*4 .. w*4+3 (units w*64..w*64+63)
  const int l    = j & 63;
  const int col  = l & 15;
  const int quad = l >> 4;

  // B-fragments register-resident (loaded once, reused for all 8 m-tiles)
  short8 Breg[4][4];
#pragma unroll
  for (int i = 0; i < 4; i++)
#pragma unroll
    for (int ks = 0; ks < 4; ks++)
      Breg[i][ks] = WhB[(ks * 16 + (w * 4 + i)) * 64 + l];

  float wh0r[4], zhr[4], wmur[4], wsgr[4];
#pragma unroll
  for (int i = 0; i < 4; i++) {
    int u = w * 64 + i * 16 + col;
    wh0r[i] = wh0s[u]; zhr[i] = zhs[u];
    wmur[i] = wmus[LD + u]; wsgr[i] = wsgs[LD + u];
  }
  float wml[8], wsl[8];
#pragma unroll
  for (int q = 0; q < 8; q++) {
    wml[q] = wmus[col * 8 + q];
    wsl[q] = wsgs[col * 8 + q];
  }

  for (int mt = 0; mt < DPTS / 16; mt++) {   // 8 m-tiles of 16 points
    short8 af[4];
#pragma unroll
    for (int ks = 0; ks < 4; ks++)
      af[ks] = *(const short8*)&latA[(mt * 16 + col) * 136 + ks * 32 + quad * 8];
    v4f acc[4];
#pragma unroll
    for (int i = 0; i < 4; i++) acc[i] = (v4f){0.f, 0.f, 0.f, 0.f};
#pragma unroll
    for (int i = 0; i < 4; i++)
#pragma unroll
      for (int ks = 0; ks < 4; ks++)
        acc[i] = __builtin_amdgcn_mfma_f32_16x16x32_bf16(
            af[ks], Breg[i][ks], acc[i], 0, 0, 0);

    float m4[4] = {0.f, 0.f, 0.f, 0.f}, s4[4] = {0.f, 0.f, 0.f, 0.f};
    float xr[4];
#pragma unroll
    for (int r = 0; r < 4; r++) xr[r] = xv[mt * 16 + quad * 4 + r];
#pragma unroll
    for (int i = 0; i < 4; i++)
#pragma unroll
      for (int r = 0; r < 4; r++) {
        float h = fmaxf(acc[i][r] + xr[r] * wh0r[i] + zhr[i], 0.f);
        m4[r] += h * wmur[i];
        s4[r] += h * wsgr[i];
      }
    if (w == 0) {   // latent-direct term added exactly once
#pragma unroll
      for (int r = 0; r < 4; r++) {
        int t = mt * 16 + quad * 4 + r;
        uint4 lw = *(const uint4*)&latA[t * 136 + col * 8];
        float l0 = bf_lo(lw.x), l1 = bf_hi(lw.x), l2 = bf_lo(lw.y), l3 = bf_hi(lw.y);
        float l4 = bf_lo(lw.z), l5 = bf_hi(lw.z), l6 = bf_lo(lw.w), l7 = bf_hi(lw.w);
        m4[r] += l0 * wml[0] + l1 * wml[1] + l2 * wml[2] + l3 * wml[3]
               + l4 * wml[4] + l5 * wml[5] + l6 * wml[6] + l7 * wml[7];
        s4[r] += l0 * wsl[0] + l1 * wsl[1] + l2 * wsl[2] + l3 * wsl[3]
               + l4 * wsl[4] + l5 * wsl[5] + l6 * wsl[6] + l7 * wsl[7];
      }
    }
#pragma unroll
    for (int r = 0; r < 4; r++) {
#pragma unroll
      for (int m = 1; m <= 8; m <<= 1) {
        m4[r] += __shfl_xor(m4[r], m);
        s4[r] += __shfl_xor(s4[r], m);
      }
    }
    if (col == 0) {
#pragma unroll
      for (int r = 0; r < 4; r++) {
        int t = mt * 16 + quad * 4 + r;
        pmu[w][t] = m4[r];
        psg[w][t] = s4[r];
      }
    }
  }
  __syncthreads();

  if (j < DPTS) {
    float m  = (pmu[0][j] + pmu[1][j]) + (pmu[2][j] + pmu[3][j]) + bmu[0];
    float sv = (psg[0][j] + psg[1][j]) + (psg[2][j] + psg[3][j]) + bsig[0];
    out[(size_t)b * P_SZ + p0 + j] = m;
    float sp = (sv > 20.f) ? sv : log1pf(__expf(sv));
    out[(size_t)B_SZ * P_SZ + b * P_SZ + p0 + j] = 0.1f + 0.9f * sp;
  }
}

// ---------------------------------------------------------------------------
extern "C" void kernel_launch(void* const* d_in, const int* in_sizes, int n_in,
                              void* d_out, int out_size, void* d_ws, size_t ws_size,
                              hipStream_t stream) {
  const float* x    = (const float*)d_in[0];
  const float* z    = (const float*)d_in[1];
  const float* x0   = (const float*)d_in[2];
  const float* W1   = (const float*)d_in[3];
  const float* b1   = (const float*)d_in[4];
  const float* W2   = (const float*)d_in[5];
  const float* b2   = (const float*)d_in[6];
  const float* W3   = (const float*)d_in[7];
  const float* b3   = (const float*)d_in[8];
  const float* Wh   = (const float*)d_in[9];
  const float* bh   = (const float*)d_in[10];
  const float* Wmu  = (const float*)d_in[11];
  const float* bmu  = (const float*)d_in[12];
  const float* Wsig = (const float*)d_in[13];
  const float* bsig = (const float*)d_in[14];
  float* out = (float*)d_out;

  char* ws = (char*)d_ws;
  float* zh     = (float*)ws;                      //  0       256 KB
  float* dstate = (float*)(ws + 262144);           // +256 KB  512 KB
  uint4* W1B    = (uint4*)(ws + 786432);           //  64 KB
  uint4* W1hB   = (uint4*)(ws + 851968);           //  64 KB
  uint4* W2B    = (uint4*)(ws + 917504);           // 128 KB
  uint4* W3B    = (uint4*)(ws + 1048576);          //  64 KB
  uint4* WhB    = (uint4*)(ws + 1114112);          //  64 KB

  pack_kernel<<<dim3(80), dim3(256), 0, stream>>>(
      W1, W2, W3, W1B, W1hB, W2B, W3B);
  ode_plus_kernel<<<dim3(84), dim3(1024), 0, stream>>>(
      x, z, x0, W1, b1, b2, b3, Wh, bh,
      (const short8*)W1B, (const short8*)W1hB,
      (const short8*)W2B, (const short8*)W3B, dstate, zh, WhB);
  decode_kernel<<<dim3(P_SZ / DPTS, B_SZ), dim3(256), 0, stream>>>(
      x, x0, dstate, zh, Wh, (const short8*)WhB, Wmu, bmu, Wsig, bsig, out);
}